// Round 7
// baseline (658.807 us; speedup 1.0000x reference)
//
#include <hip/hip_runtime.h>
#include <hip/hip_fp16.h>
#include <stdint.h>

typedef _Float16 f16;
typedef _Float16 f16x8 __attribute__((ext_vector_type(8)));
typedef _Float16 f16x4 __attribute__((ext_vector_type(4)));
typedef __fp16 h16x4 __attribute__((ext_vector_type(4)));
typedef float f32x4 __attribute__((ext_vector_type(4)));
typedef uint32_t u32x4 __attribute__((ext_vector_type(4)));
typedef uint32_t u32x2 __attribute__((ext_vector_type(2)));

#define NB 256
#define NT 256
#define ND 300
#define NH 200
#define NOUT 100
#define C3H 600
#define NTILE 40          // xproj B tiles (39 real sectioned tiles + 1 dummy)
#define NKCX 10           // K=300 -> 320 = 10 chunks of 32
#define NKCH 7            // K=200 -> 6 chunks of 32 + 1 tail chunk (k=192..199)
#define WHT 48            // whp tile space: 16 triples x 3 sections
#define SLABF 9984        // f16 per (dir,t,bg) xp slab: 39 chunks x 64 lanes x 4
#define SLABB 19968       // bytes per slab
#define LOG2E 1.44269504088896f

#define XP_BYTES   (2ull * NT * 16 * SLABB)          // 163,577,856
#define WXP_BYTES  (2ull * NKCX * NTILE * 512 * 2)   // 819,200
#define WHP_BYTES  (2ull * NKCH * WHT * 512 * 2)     // 688,128

typedef const __attribute__((address_space(1))) uint32_t ga_u32;
typedef __attribute__((address_space(3))) uint32_t lds_u32;

#if __has_builtin(__builtin_amdgcn_mfma_f32_16x16x16f16)
#define TAIL16 1
#else
#define TAIL16 0
#endif

__device__ __forceinline__ float fast_exp2(float x) {
#if __has_builtin(__builtin_amdgcn_exp2f)
  return __builtin_amdgcn_exp2f(x);
#else
  return exp2f(x);
#endif
}
__device__ __forceinline__ float fast_rcp(float x) {
#if __has_builtin(__builtin_amdgcn_rcpf)
  return __builtin_amdgcn_rcpf(x);
#else
  return 1.f / x;
#endif
}

// ---------------------------------------------------------------------------
// Sectioned column space: col600 = s*200 + (ii*16 + c). exp2 pre-scaling baked
// in (z/r: x -log2e; h: x 2*log2e). Wh K-chunking: kc 0..5 full 32 (k<192),
// kc 6 = tail. Tail mapping (must match birnn's A-read bijection):
//   TAIL16: k = 192 + (lane>>4)*4 + j, j<4 (16x16x16 frag, 4 f16/lane)
//   else:   k = 192 + (lane>>4)*8 + j  (16x16x32 frag, upper k zero-padded)
// ---------------------------------------------------------------------------
__global__ void pack_w(const float* __restrict__ Wxf, const float* __restrict__ Wxb,
                       const float* __restrict__ Whf, const float* __restrict__ Whb,
                       f16* __restrict__ wxp, f16* __restrict__ whp) {
  int e = blockIdx.x * 256 + threadIdx.x;
  const int NX = 2 * NKCX * NTILE * 512;     // 409,600
  const int NHW = 2 * NKCH * WHT * 512;      // 344,064
  if (e < NX) {
    int j = e & 7, lane = (e >> 3) & 63;
    int tile = (e >> 9) % NTILE;
    int kc = ((e >> 9) / NTILE) % NKCX;
    int dir = (e >> 9) / (NTILE * NKCX);
    int k = kc * 32 + ((lane >> 4) * 8) + j;
    int c = lane & 15;
    float v = 0.f;
    if (tile < 39) {
      int s = tile / 13, ii = tile % 13;
      int hc = ii * 16 + c;
      if (k < ND && hc < NH) {
        const float* W = dir ? Wxb : Wxf;
        float sc = (s == 2) ? 2.f * LOG2E : -LOG2E;
        v = W[k * C3H + s * NH + hc] * sc;
      }
    }
    wxp[e] = (f16)v;
  } else if (e < NX + NHW) {
    int e2 = e - NX;
    int j = e2 & 7, lane = (e2 >> 3) & 63;
    int tile = (e2 >> 9) % WHT;
    int kc = ((e2 >> 9) / WHT) % NKCH;
    int dir = (e2 >> 9) / (WHT * NKCH);
    int tp = tile / 3, s = tile % 3;
    int c = lane & 15;
    int k;
    bool kvalid;
    if (kc < 6) {
      k = kc * 32 + ((lane >> 4) * 8) + j;   // always < 192: real
      kvalid = true;
    } else {
#if TAIL16
      k = 192 + ((lane >> 4) * 4) + j;       // j<4 only
      kvalid = (j < 4) && (k < NH);
#else
      k = 192 + ((lane >> 4) * 8) + j;
      kvalid = (k < NH);
#endif
    }
    float v = 0.f;
    if (tp < 13) {
      int hc = tp * 16 + c;
      if (kvalid && hc < NH) {
        const float* W = dir ? Whb : Whf;
        float sc = (s == 2) ? 2.f * LOG2E : -LOG2E;
        v = W[k * C3H + s * NH + hc] * sc;
      }
    }
    whp[e2] = (f16)v;
  }
}

// ---------------------------------------------------------------------------
// xproj: 1024 threads, 16 waves = 2 row-halves x 8 col-groups; per-wave
// acc[4][5] = 80 VGPRs (fits the 128 cap -- R5's 8-wave version spilled
// acc[8][5]=160). BM=128 rows (one t, half the batch), output written in the
// MFMA C-fragment layout birnn's gate lanes consume.
// ---------------------------------------------------------------------------
__global__ __launch_bounds__(1024) void xproj(
    const float* __restrict__ x, const int* __restrict__ len,
    const f16* __restrict__ wxp,
    const float* __restrict__ bxf, const float* __restrict__ bxb,
    const float* __restrict__ bhf, const float* __restrict__ bhb,
    f16* __restrict__ xp) {
  __shared__ f16 As[128 * 328];   // 83,968 B (stride 656 B = 16*41: aligned)
  __shared__ f16 Bs[NTILE * 512]; // 40,960 B
  int blk = blockIdx.x;
  int dir = blk >> 9;
  int m0 = (blk & 511) * 128;
  int t = m0 >> 8;
  int bstart = m0 & 255;
  int tid = threadIdx.x;
  int lane = tid & 63, w = tid >> 6;      // 16 waves
  int g = lane >> 4, c = lane & 15;
  int rh = w >> 3, cg = w & 7;

  { // stage A: 128 rows x 300 fp32 -> f16, K padded to 320; 8 threads/row
    int r = tid >> 3, q = tid & 7;
    int b = bstart + r;
    int srct = t;
    if (dir) { int L = len[b]; srct = L - 1 - t; if (srct < 0) srct = 0; }
    const float* xrow = x + ((size_t)b * NT + srct) * ND;
#pragma unroll
    for (int s = 0; s < 10; ++s) {
      int i4 = q + 8 * s;                  // 0..79 (75 real)
      f16x4 h4;
      if (i4 < 75) {
        float4 v = *(const float4*)(xrow + 4 * i4);
        h4 = (f16x4){(f16)v.x, (f16)v.y, (f16)v.z, (f16)v.w};
      } else {
        h4 = (f16x4){(f16)0.f, (f16)0.f, (f16)0.f, (f16)0.f};
      }
      *(f16x4*)(&As[r * 328 + 4 * i4]) = h4;
    }
  }

  f32x4 acc[4][5];
#pragma unroll
  for (int rt = 0; rt < 4; ++rt)
#pragma unroll
    for (int i = 0; i < 5; ++i) acc[rt][i] = (f32x4){0.f, 0.f, 0.f, 0.f};

  const f16* wxp_d = wxp + (size_t)dir * NKCX * NTILE * 512;
  for (int kc = 0; kc < NKCX; ++kc) {
#pragma unroll
    for (int i = 0; i < 3; ++i) {
      int idx = w + 16 * i;
      if (idx < NTILE) {
        const f16* src = wxp_d + ((size_t)kc * NTILE + idx) * 512 + lane * 8;
        __builtin_amdgcn_global_load_lds((ga_u32*)src, (lds_u32*)(&Bs[idx * 512]), 16, 0, 0);
      }
    }
    __syncthreads();
#pragma unroll
    for (int rt = 0; rt < 4; ++rt) {
      f16x8 af = *(const f16x8*)(&As[((rh * 4 + rt) * 16 + c) * 328 + kc * 32 + g * 8]);
#pragma unroll
      for (int i = 0; i < 5; ++i) {
        f16x8 bf = *(const f16x8*)(&Bs[(cg * 5 + i) * 512 + lane * 8]);
        acc[rt][i] = __builtin_amdgcn_mfma_f32_16x16x32_f16(af, bf, acc[rt][i], 0, 0, 0);
      }
    }
    __syncthreads();
  }

  const float* bx = dir ? bxb : bxf;
  const float* bh = dir ? bhb : bhf;
#pragma unroll
  for (int i = 0; i < 5; ++i) {
    int tile = cg * 5 + i;
    if (tile >= 39) continue;
    int s = tile / 13, ii = tile % 13;
    int hc = ii * 16 + c;
    float addv = 0.f;
    if (hc < NH) {
      int col600 = s * NH + hc;
      float sc = (s == 2) ? 2.f * LOG2E : -LOG2E;
      addv = (bx[col600] + (s < 2 ? bh[col600] : 0.f)) * sc;
    }
#pragma unroll
    for (int rt = 0; rt < 4; ++rt) {
      int bg = (bstart >> 4) + rh * 4 + rt;
      f16* dst = xp + (((size_t)dir * NT + t) * 16 + bg) * SLABF + ((ii * 3 + s) * 64 + lane) * 4;
      f16x4 v4 = {(f16)(acc[rt][i][0] + addv), (f16)(acc[rt][i][1] + addv),
                  (f16)(acc[rt][i][2] + addv), (f16)(acc[rt][i][3] + addv)};
      *(f16x4*)dst = v4;
    }
  }
}

// ---------------------------------------------------------------------------
// Persistent bidirectional GRU. 32 blocks = 2 dirs x 16 groups of 16 rows.
// 13 waves (832 thr): wave w owns triple w (cols w*16..w*16+15). Wh per wave:
// whu[3][6] (72 VGPR) + 16x16x16 tail (6 VGPR) = 78 -> total ~124, under the
// 128 cap WITHOUT occupancy attributes (R2/R5 lesson: the cap stays 128, so
// fit it). xp read per step straight into registers (coalesced dwordx2 from
// L3-resident xp, issued before MFMA -> latency hidden). LDS = h only.
// ---------------------------------------------------------------------------
__global__ __launch_bounds__(832) void birnn(
    const f16* __restrict__ xp, const f16* __restrict__ whp,
    const int* __restrict__ len,
    const float* __restrict__ bhf, const float* __restrict__ bhb,
    float* __restrict__ sums) {
  __shared__ f16 hls[2][16 * 232];   // [row][k-col], stride 464 B = 16*29
  int blk = blockIdx.x;
  int dir = blk >> 4;
  int b0 = (blk & 15) << 4;
  int tid = threadIdx.x;
  int lane = tid & 63, w = tid >> 6;   // w = triple 0..12
  int g = lane >> 4, c = lane & 15;
  int hc = w * 16 + c;                 // this lane's h-column (gate side)

  u32x4 whu[3][6];
#if TAIL16
  u32x2 wht[3];
#else
  u32x4 wht[3];
#endif
  const f16* whp_d = whp + (size_t)dir * NKCH * WHT * 512;
#pragma unroll
  for (int s = 0; s < 3; ++s) {
#pragma unroll
    for (int kc = 0; kc < 6; ++kc)
      whu[s][kc] = *(const u32x4*)(whp_d + ((size_t)(kc * WHT + w * 3 + s)) * 512 + lane * 8);
#if TAIL16
    wht[s] = *(const u32x2*)(whp_d + ((size_t)(6 * WHT + w * 3 + s)) * 512 + lane * 8);
#else
    wht[s] = *(const u32x4*)(whp_d + ((size_t)(6 * WHT + w * 3 + s)) * 512 + lane * 8);
#endif
  }
#pragma unroll
  for (int s = 0; s < 3; ++s) {
#pragma unroll
    for (int kc = 0; kc < 6; ++kc) asm volatile("" : "+v"(whu[s][kc]));
    asm volatile("" : "+v"(wht[s]));
  }

  for (int o = tid; o < 2 * 16 * 232; o += 832) ((f16*)hls)[o] = (f16)0.f;

  int lenpack = 0;                     // 4 x u8 (len-1), unpacked via BFE
#pragma unroll
  for (int jj = 0; jj < 4; ++jj) lenpack |= (len[b0 + g * 4 + jj] - 1) << (8 * jj);
  int maxlen = 0;
  for (int i = 0; i < 16; ++i) { int L = len[b0 + i]; maxlen = L > maxlen ? L : maxlen; }

  const float* bh = dir ? bhb : bhf;
  float bhh = (hc < NH) ? bh[2 * NH + hc] * (2.f * LOG2E) : 0.f;
  f16x4 hreg = {};
  f32x4 sum = {(f32x4){0.f, 0.f, 0.f, 0.f}};

  const char* xrow = (const char*)xp
      + (((size_t)dir * NT) * 16 + (size_t)(blk & 15)) * (size_t)SLABB
      + (size_t)(w * 3) * 512 + (size_t)lane * 8;

  __syncthreads();

  for (int t = 0; t < maxlen; ++t) {
    int cur = t & 1, nxt = cur ^ 1;
    // xp for this step: 3 coalesced 8B/lane loads, consumed only in the gate
    u32x2 xzv = *(const u32x2*)(xrow);
    u32x2 xrv = *(const u32x2*)(xrow + 512);
    u32x2 xhv = *(const u32x2*)(xrow + 1024);
    xrow += (size_t)16 * SLABB;

    // rec = h @ Wh : A from LDS h fragments (shared), B resident in VGPRs
    f32x4 a0 = {0.f,0.f,0.f,0.f}, a1 = {0.f,0.f,0.f,0.f}, a2 = {0.f,0.f,0.f,0.f};
    const f16* hb = &hls[cur][c * 232 + g * 8];
#pragma unroll
    for (int kc = 0; kc < 6; ++kc) {
      f16x8 af = *(const f16x8*)(hb + kc * 32);
      a0 = __builtin_amdgcn_mfma_f32_16x16x32_f16(af, __builtin_bit_cast(f16x8, whu[0][kc]), a0, 0, 0, 0);
      a1 = __builtin_amdgcn_mfma_f32_16x16x32_f16(af, __builtin_bit_cast(f16x8, whu[1][kc]), a1, 0, 0, 0);
      a2 = __builtin_amdgcn_mfma_f32_16x16x32_f16(af, __builtin_bit_cast(f16x8, whu[2][kc]), a2, 0, 0, 0);
    }
#if TAIL16
    {
      h16x4 at = *(const h16x4*)(&hls[cur][c * 232 + 192 + g * 4]);
      a0 = __builtin_amdgcn_mfma_f32_16x16x16f16(at, __builtin_bit_cast(h16x4, wht[0]), a0, 0, 0, 0);
      a1 = __builtin_amdgcn_mfma_f32_16x16x16f16(at, __builtin_bit_cast(h16x4, wht[1]), a1, 0, 0, 0);
      a2 = __builtin_amdgcn_mfma_f32_16x16x16f16(at, __builtin_bit_cast(h16x4, wht[2]), a2, 0, 0, 0);
    }
#else
    {
      f16x8 at = *(const f16x8*)(&hls[cur][c * 232 + 192 + g * 8]);
      a0 = __builtin_amdgcn_mfma_f32_16x16x32_f16(at, __builtin_bit_cast(f16x8, wht[0]), a0, 0, 0, 0);
      a1 = __builtin_amdgcn_mfma_f32_16x16x32_f16(at, __builtin_bit_cast(f16x8, wht[1]), a1, 0, 0, 0);
      a2 = __builtin_amdgcn_mfma_f32_16x16x32_f16(at, __builtin_bit_cast(f16x8, wht[2]), a2, 0, 0, 0);
    }
#endif

    if (hc < NH) {
      f16x4 xz4 = __builtin_bit_cast(f16x4, xzv);
      f16x4 xr4 = __builtin_bit_cast(f16x4, xrv);
      f16x4 xh4 = __builtin_bit_cast(f16x4, xhv);
      float hn[4];
#pragma unroll
      for (int jj = 0; jj < 4; ++jj) {
        float az = (float)xz4[jj] + a0[jj];
        float z  = fast_rcp(1.f + fast_exp2(az));
        float ar = (float)xr4[jj] + a1[jj];
        float r  = fast_rcp(1.f + fast_exp2(ar));
        float c2 = fmaf(r, a2[jj] + bhh, (float)xh4[jj]);
        float th = fmaf(-2.f, fast_rcp(1.f + fast_exp2(c2)), 1.f);
        float hold = (float)hreg[jj];
        float v = fmaf(z, hold - th, th);
        bool va = t <= ((lenpack >> (8 * jj)) & 255);
        v = va ? v : hold;
        sum[jj] += va ? v : 0.f;
        hn[jj] = v;
      }
      uint32_t plo = __builtin_bit_cast(uint32_t, __builtin_amdgcn_cvt_pkrtz(hn[0], hn[1]));
      uint32_t phi = __builtin_bit_cast(uint32_t, __builtin_amdgcn_cvt_pkrtz(hn[2], hn[3]));
      hreg = __builtin_bit_cast(f16x4, (u32x2){plo, phi});
#pragma unroll
      for (int jj = 0; jj < 4; ++jj)
        hls[nxt][(g * 4 + jj) * 232 + hc] = hreg[jj];
    }
    __syncthreads();
  }

  if (hc < NH) {
#pragma unroll
    for (int jj = 0; jj < 4; ++jj)
      sums[((size_t)dir * NB + b0 + g * 4 + jj) * NH + hc] = sum[jj];
  }
}

// ---------------------------------------------------------------------------
// out[b][o] = tanh( (concat(sum_f,sum_b)/L^2) @ Wd + bd )
// ---------------------------------------------------------------------------
__global__ void head_k(const float* __restrict__ sums, const int* __restrict__ len,
                       const float* __restrict__ Wd, const float* __restrict__ bd,
                       float* __restrict__ out) {
  __shared__ float pl[2 * NH];
  int b = blockIdx.x, tid = threadIdx.x;
  float L = (float)len[b];
  float inv = 1.f / (L * L);
  for (int k = tid; k < 2 * NH; k += 128) {
    int d = k < NH ? 0 : 1;
    int j = k < NH ? k : k - NH;
    pl[k] = sums[((size_t)d * NB + b) * NH + j] * inv;
  }
  __syncthreads();
  if (tid < NOUT) {
    float a = bd[tid];
    for (int k = 0; k < 2 * NH; ++k) a = fmaf(pl[k], Wd[k * NOUT + tid], a);
    out[b * NOUT + tid] = tanhf(a);
  }
}

extern "C" void kernel_launch(void* const* d_in, const int* in_sizes, int n_in,
                              void* d_out, int out_size, void* d_ws, size_t ws_size,
                              hipStream_t stream) {
  const float* x   = (const float*)d_in[0];
  const int*   len = (const int*)d_in[1];
  const float* Wxf = (const float*)d_in[2];
  const float* Whf = (const float*)d_in[3];
  const float* bxf = (const float*)d_in[4];
  const float* bhf = (const float*)d_in[5];
  const float* Wxb = (const float*)d_in[6];
  const float* Whb = (const float*)d_in[7];
  const float* bxb = (const float*)d_in[8];
  const float* bhb = (const float*)d_in[9];
  const float* Wd  = (const float*)d_in[10];
  const float* bd  = (const float*)d_in[11];
  float* out = (float*)d_out;
  char* ws = (char*)d_ws;
  f16* xp  = (f16*)(ws);
  f16* wxp = (f16*)(ws + XP_BYTES + 1024);           // 1KB pad: staging overread
  f16* whp = (f16*)(ws + XP_BYTES + 1024 + WXP_BYTES);
  float* sums = (float*)(ws + XP_BYTES + 1024 + WXP_BYTES + WHP_BYTES);

  hipLaunchKernelGGL(pack_w, dim3(2944), dim3(256), 0, stream,
                     Wxf, Wxb, Whf, Whb, wxp, whp);
  hipLaunchKernelGGL(xproj, dim3(1024), dim3(1024), 0, stream,
                     x, len, wxp, bxf, bxb, bhf, bhb, xp);
  hipLaunchKernelGGL(birnn, dim3(32), dim3(832), 0, stream,
                     xp, whp, len, bhf, bhb, sums);
  hipLaunchKernelGGL(head_k, dim3(256), dim3(128), 0, stream,
                     sums, len, Wd, bd, out);
}